// Round 18
// baseline (121.108 us; speedup 1.0000x reference)
//
#include <hip/hip_runtime.h>
#include <hip/hip_fp16.h>
#include <math.h>

#define B_ 4096
#define L_ 50
#define D_ 200
#define A_ 14
#define S_ 30

// ws layout (floats)
#define WS_HYP   0
#define WS_KLE   (A_ * D_)
#define WS_Y2    (2 * A_ * D_)
#define WS_LF    (WS_Y2 + A_)
#define WS_MH    8192                      // Mh: 40000 halves = 20000 floats
#define WS_EMBH  (WS_MH + 20000)           // embh: 10M halves = 5M floats
#define EMBH_FLOATS ((50000 * D_) / 2)
#define WS_V     8192                      // fallback f32 path only

// ---------- helpers ----------
__device__ __forceinline__ float wave_reduce_sum(float v) {
    #pragma unroll
    for (int off = 32; off > 0; off >>= 1) v += __shfl_down(v, off, 64);
    return v;
}
__device__ __forceinline__ float bfly_sum(float v) {
    #pragma unroll
    for (int m = 32; m > 0; m >>= 1) v += __shfl_xor(v, m, 64);
    return v;
}
__device__ __forceinline__ float bfly_max(float v) {
    #pragma unroll
    for (int m = 32; m > 0; m >>= 1) v = fmaxf(v, __shfl_xor(v, m, 64));
    return v;
}
__device__ __forceinline__ float bfly_sum16(float v) {
    #pragma unroll
    for (int m = 8; m > 0; m >>= 1) v += __shfl_xor(v, m, 64);
    return v;
}
__device__ __forceinline__ float block_reduce_512(float val, volatile float* red) {
    __syncthreads();
    val = wave_reduce_sum(val);
    if ((threadIdx.x & 63) == 0) red[threadIdx.x >> 6] = val;
    __syncthreads();
    float s = 0.f;
    #pragma unroll
    for (int i = 0; i < 8; ++i) s += red[i];
    return s;
}

typedef _Float16 h2v __attribute__((ext_vector_type(2)));
__device__ __forceinline__ float fd2(unsigned a, unsigned b, float c) {
#if __has_builtin(__builtin_amdgcn_fdot2)
    return __builtin_amdgcn_fdot2(__builtin_bit_cast(h2v, a),
                                  __builtin_bit_cast(h2v, b), c, false);
#else
    __half2 ha = __builtin_bit_cast(__half2, a), hb = __builtin_bit_cast(__half2, b);
    float2 fa = __half22float2(ha), fb = __half22float2(hb);
    return fmaf(fa.x, fb.x, fmaf(fa.y, fb.y, c));
#endif
}
__device__ __forceinline__ unsigned packh2(float a, float b) {
    __half2 h = __floats2half2_rn(a, b);
    return __builtin_bit_cast(unsigned, h);
}

// ---------- device body: anchor precompute (runs in one block) ----------
__device__ void anchors_body(const float* __restrict__ a_emb,
                             const float* __restrict__ seed_w,
                             float* __restrict__ ws)
{
    __shared__ float u[A_][D_];
    __shared__ float nrm2[A_];
    const int t = threadIdx.x;
    const int wave = t >> 6, lane = t & 63;

    for (int d = t; d < D_; d += 256) {
        for (int a = 0; a < A_; ++a) {
            float acc = 0.f;
            #pragma unroll 5
            for (int s = 0; s < S_; ++s)
                acc += a_emb[(a * S_ + s) * D_ + d] * seed_w[a * S_ + s];
            u[a][d] = acc;
        }
    }
    __syncthreads();

    for (int a = wave; a < A_; a += 4) {
        float s = 0.f;
        for (int d = lane; d < D_; d += 64) s += u[a][d] * u[a][d];
        s = wave_reduce_sum(s);
        if (lane == 0) nrm2[a] = s;
    }
    __syncthreads();

    float* hyp = ws + WS_HYP;
    float* kle = ws + WS_KLE;
    float* y2  = ws + WS_Y2;
    float* lf  = ws + WS_LF;
    const float maxn = 1.0f - 1e-5f;

    for (int a = 0; a < A_; ++a) {
        float un = fmaxf(sqrtf(nrm2[a]), 1e-15f);
        float th = tanhf(un);
        float pn = fminf(th, maxn);
        float s  = pn / un;
        float py2 = pn * pn;
        float kscale = 2.0f / (1.0f + py2);
        float k2 = py2 * kscale * kscale;
        if (t == 0) {
            y2[a] = py2;
            lf[a] = 1.0f / sqrtf(fmaxf(1.0f - k2, 1e-7f));
        }
        for (int d = t; d < D_; d += 256) {
            float h = u[a][d] * s;
            hyp[a * D_ + d] = h;
            kle[a * D_ + d] = h * kscale;
        }
    }
}

// ---------- kernel 0 (merged): anchors (block 0) + emb/M f32->f16 convert ----------
__global__ __launch_bounds__(256) void prep_all(
    const float* __restrict__ a_emb, const float* __restrict__ seed_w,
    const float* __restrict__ emb,   const float* __restrict__ M,
    float* __restrict__ ws, __half* __restrict__ embh, __half* __restrict__ Mh)
{
    if (blockIdx.x == 0) {
        anchors_body(a_emb, seed_w, ws);
        return;
    }
    const int nb = gridDim.x - 1;              // converter blocks
    const int cb = blockIdx.x - 1;
    const int n4e = (50000 * D_) / 4;          // 2,500,000
    const int n4m = (D_ * D_) / 4;             // 10,000
    for (int i = cb * 256 + threadIdx.x; i < n4e + n4m; i += nb * 256) {
        if (i < n4e) {
            float4 v = ((const float4*)emb)[i];
            uint2 u; u.x = packh2(v.x, v.y); u.y = packh2(v.z, v.w);
            ((uint2*)embh)[i] = u;
        } else {
            const int j = i - n4e;
            float4 v = ((const float4*)M)[j];
            uint2 u; u.x = packh2(v.x, v.y); u.y = packh2(v.z, v.w);
            ((uint2*)Mh)[j] = u;
        }
    }
}

// ---------- standalone anchors (fallback paths) ----------
__global__ __launch_bounds__(256) void precompute_anchors(
    const float* __restrict__ a_emb, const float* __restrict__ seed_w,
    float* __restrict__ ws)
{
    anchors_body(a_emb, seed_w, ws);
}

// ---------- kernel (primary): R12 structure, fp16 loads, 8 waves/SIMD ----------
__global__ __launch_bounds__(256, 8) void fused_wave2_h(
    const int*   __restrict__ inputs,
    const float* __restrict__ ws,
    float* __restrict__ out)
{
    __shared__ float xav[2][2][D_];
    __shared__ float vsh[2][D_];
    __shared__ float ench[2][2][D_];
    __shared__ float msh[2][2][2];

    const float*  kle  = ws + WS_KLE;
    const float*  y2   = ws + WS_Y2;
    const float*  lf   = ws + WS_LF;
    const __half* Mh   = (const __half*)(ws + WS_MH);
    const __half* embh = (const __half*)(ws + WS_EMBH);

    const int wid  = threadIdx.x >> 6, lane = threadIdx.x & 63;
    const int rib  = wid >> 1;
    const int h    = wid & 1;
    const int b    = blockIdx.x * 2 + rib;
    const bool L50 = (lane < 50);

    const int sidx = inputs[b * L_ + (L50 ? lane : 0)];
    const int offh = L50 ? 4 * lane : 0;        // half-units
    const int lbase = 25 * h;

    // ---- P1: x_avg partials over this wave's 25 rows (fp16 loads) ----
    float a0 = 0.f, a1 = 0.f, a2 = 0.f, a3 = 0.f;
    #pragma unroll 5
    for (int j = 0; j < 25; ++j) {
        const int row = __shfl(sidx, lbase + j, 64);
        uint2 u = *(const uint2*)(embh + (size_t)row * D_ + offh);
        float2 f0 = __half22float2(__builtin_bit_cast(__half2, u.x));
        float2 f1 = __half22float2(__builtin_bit_cast(__half2, u.y));
        a0 += f0.x; a1 += f0.y; a2 += f1.x; a3 += f1.y;
    }
    if (L50) {
        xav[rib][h][4 * lane + 0] = a0;
        xav[rib][h][4 * lane + 1] = a1;
        xav[rib][h][4 * lane + 2] = a2;
        xav[rib][h][4 * lane + 3] = a3;
    }
    __syncthreads();
    unsigned xu0 = 0, xu1 = 0;
    if (L50) {
        const float inv = 1.0f / (float)L_;
        float f0 = (xav[rib][0][4*lane+0] + xav[rib][1][4*lane+0]) * inv;
        float f1 = (xav[rib][0][4*lane+1] + xav[rib][1][4*lane+1]) * inv;
        float f2 = (xav[rib][0][4*lane+2] + xav[rib][1][4*lane+2]) * inv;
        float f3 = (xav[rib][0][4*lane+3] + xav[rib][1][4*lane+3]) * inv;
        xu0 = packh2(f0, f1);
        xu1 = packh2(f2, f3);
    }

    // ---- P2: v for dims [100h, 100h+100): lane owns 2 M rows (fp16, fdot2) ----
    {
        float w0 = 0.f, w1 = 0.f;
        const int mr = 100 * h + 2 * (L50 ? lane : 0);
        const __half* m0 = Mh + (size_t)(mr + 0) * D_;
        const __half* m1 = Mh + (size_t)(mr + 1) * D_;
        #pragma unroll 5
        for (int c = 0; c < 25; ++c) {
            unsigned xa = __shfl(xu0, 2 * c,     64);
            unsigned xb = __shfl(xu1, 2 * c,     64);
            unsigned xc = __shfl(xu0, 2 * c + 1, 64);
            unsigned xd = __shfl(xu1, 2 * c + 1, 64);
            uint4 q0 = *(const uint4*)(m0 + 8 * c);
            uint4 q1 = *(const uint4*)(m1 + 8 * c);
            w0 = fd2(q0.x, xa, w0); w0 = fd2(q0.y, xb, w0); w0 = fd2(q0.z, xc, w0); w0 = fd2(q0.w, xd, w0);
            w1 = fd2(q1.x, xa, w1); w1 = fd2(q1.y, xb, w1); w1 = fd2(q1.z, xc, w1); w1 = fd2(q1.w, xd, w1);
        }
        if (L50) { vsh[rib][mr] = w0; vsh[rib][mr + 1] = w1; }
    }
    __syncthreads();
    float v0 = 0.f, v1 = 0.f, v2 = 0.f, v3 = 0.f;
    if (L50) {
        v0 = vsh[rib][4 * lane + 0];
        v1 = vsh[rib][4 * lane + 1];
        v2 = vsh[rib][4 * lane + 2];
        v3 = vsh[rib][4 * lane + 3];
    }

    // ---- P3: flash-online over this wave's 25 rows, 5-deep dbuf (fp16) ----
    float m = -INFINITY, ssum = 0.f;
    float e0 = 0.f, e1 = 0.f, e2 = 0.f, e3 = 0.f;
    {
        uint2 bufA[5], bufB[5];
        auto LOADC = [&](uint2* xb, int base) {
            #pragma unroll
            for (int j = 0; j < 5; ++j) {
                const int r = __shfl(sidx, lbase + base + j, 64);
                xb[j] = *(const uint2*)(embh + (size_t)r * D_ + offh);
            }
        };
        auto PROC = [&](const uint2* xb) {
            #pragma unroll
            for (int j = 0; j < 5; ++j) {
                float2 f0 = __half22float2(__builtin_bit_cast(__half2, xb[j].x));
                float2 f1 = __half22float2(__builtin_bit_cast(__half2, xb[j].y));
                float part = L50 ? (f0.x * v0 + f0.y * v1 + f1.x * v2 + f1.y * v3) : 0.f;
                const float s = bfly_sum(part);
                if (s > m) {
                    const float r = expf(m - s);
                    ssum *= r; e0 *= r; e1 *= r; e2 *= r; e3 *= r;
                    m = s;
                }
                const float w = expf(s - m);
                ssum += w;
                e0 = fmaf(w, f0.x, e0); e1 = fmaf(w, f0.y, e1);
                e2 = fmaf(w, f1.x, e2); e3 = fmaf(w, f1.y, e3);
            }
        };
        LOADC(bufA, 0);
        LOADC(bufB, 5);  PROC(bufA);
        LOADC(bufA, 10); PROC(bufB);
        LOADC(bufB, 15); PROC(bufA);
        LOADC(bufA, 20); PROC(bufB);
        PROC(bufA);
    }
    if (L50) {
        ench[rib][h][4 * lane + 0] = e0;
        ench[rib][h][4 * lane + 1] = e1;
        ench[rib][h][4 * lane + 2] = e2;
        ench[rib][h][4 * lane + 3] = e3;
    }
    if (lane == 0) { msh[rib][h][0] = m; msh[rib][h][1] = ssum; }
    __syncthreads();

    // ---- merge two flash states ----
    {
        const float mo  = msh[rib][1 - h][0];
        const float sso = msh[rib][1 - h][1];
        const float M   = fmaxf(m, mo);
        const float wA  = expf(m - M);
        const float wB  = expf(mo - M);
        const float st  = ssum * wA + sso * wB;
        const float rs  = 1.0f / st;
        if (L50) {
            e0 = (e0 * wA + ench[rib][1 - h][4 * lane + 0] * wB) * rs;
            e1 = (e1 * wA + ench[rib][1 - h][4 * lane + 1] * wB) * rs;
            e2 = (e2 * wA + ench[rib][1 - h][4 * lane + 2] * wB) * rs;
            e3 = (e3 * wA + ench[rib][1 - h][4 * lane + 3] * wB) * rs;
        } else {
            e0 = e1 = e2 = e3 = 0.f;
        }
    }

    // ---- P6: expmap0 + proj ----
    const float n2 = bfly_sum(e0 * e0 + e1 * e1 + e2 * e2 + e3 * e3);
    const float un = fmaxf(sqrtf(n2), 1e-15f);
    const float pn = fminf(tanhf(un), 1.0f - 1e-5f);
    const float ps = pn / un;
    const float x2 = pn * pn;
    const float p0 = e0 * ps, p1 = e1 * ps, p2 = e2 * ps, p3 = e3 * ps;
    const int koff = L50 ? 4 * lane : 0;

    // ---- P7: dot(p, kle_a); hyp-dot = kle-dot*(1+y2)/2 ----
    float kd = 0.f;
    #pragma unroll
    for (int a = 0; a < A_; ++a) {
        float4 k = *(const float4*)(kle + a * D_ + koff);
        float part = L50 ? (p0 * k.x + p1 * k.y + p2 * k.z + p3 * k.w) : 0.f;
        float d = bfly_sum(part);
        if (lane == a) kd = d;
    }

    // ---- P8: sqdist -> probs (lane a < 14) ----
    float px = 0.f, lfv = 0.f;
    if (lane < A_) {
        const float yy  = y2[lane];
        lfv = lf[lane];
        const float dot = kd * (1.0f + yy) * 0.5f;
        const float c1 = 1.0f - 2.0f * dot + yy;
        const float c2 = 1.0f - x2;
        const float num2 = c1 * c1 * x2 - 2.0f * c1 * c2 * dot + c2 * c2 * yy;
        const float den  = fmaxf(1.0f - 2.0f * dot + x2 * yy, 1e-15f);
        const float nma  = sqrtf(fmaxf(num2, 0.f)) / den;
        const float z    = fminf(nma, 1.0f - 1e-7f);
        const float dist = logf((1.0f + z) / (1.0f - z));
        px = expf(-dist * dist - 0.05f);
    }
    const float se = bfly_sum16(px);
    const float sp = bfly_sum16(lfv * px);
    float pev = 0.f;
    if (lane < A_) {
        pev = lfv * px / sp;
        if (h == 0) {
            out[B_ * D_ + b * A_ + lane] = pev;               // probs_expanded
            out[B_ * D_ + B_ * A_ + b * A_ + lane] = px / se; // a_probs
        }
    }

    // ---- P9: Klein barycenter -> klein_to -> logmap0 ----
    float k0 = 0.f, k1 = 0.f, k2 = 0.f, k3 = 0.f;
    #pragma unroll
    for (int a = 0; a < A_; ++a) {
        const float w = __shfl(pev, a, 64);
        float4 k = *(const float4*)(kle + a * D_ + koff);
        k0 = fmaf(w, k.x, k0); k1 = fmaf(w, k.y, k1);
        k2 = fmaf(w, k.z, k2); k3 = fmaf(w, k.w, k3);
    }
    if (!L50) { k0 = k1 = k2 = k3 = 0.f; }
    const float n2k = bfly_sum(k0 * k0 + k1 * k1 + k2 * k2 + k3 * k3);
    const float denom = 1.0f + sqrtf(fmaxf(1.0f - n2k, 0.f));
    const float r2 = n2k / (denom * denom);
    const float rn = fmaxf(sqrtf(r2), 1e-15f);
    const float z2 = fminf(rn, 1.0f - 1e-7f);
    const float fac = 0.5f * logf((1.0f + z2) / (1.0f - z2)) / rn;
    if (L50 && h == 0) {
        float4 o = make_float4(fac * k0 / denom, fac * k1 / denom,
                               fac * k2 / denom, fac * k3 / denom);
        *(float4*)(out + (size_t)b * D_ + 4 * lane) = o;
    }
}

// ---------- mid-tier: R12 f32 two-pass (proven 79.7) ----------
__global__ __launch_bounds__(256) void convert_M(
    const float* __restrict__ M, __half* __restrict__ Mh)
{
    int i = blockIdx.x * 256 + threadIdx.x;
    if (i < D_ * D_) Mh[i] = __float2half(M[i]);
}

__global__ __launch_bounds__(256, 6) void fused_wave2(
    const int*   __restrict__ inputs,
    const float* __restrict__ emb,
    const float* __restrict__ ws,
    float* __restrict__ out)
{
    __shared__ float xav[2][2][D_];
    __shared__ float vsh[2][D_];
    __shared__ float ench[2][2][D_];
    __shared__ float msh[2][2][2];

    const float*  kle = ws + WS_KLE;
    const float*  y2  = ws + WS_Y2;
    const float*  lf  = ws + WS_LF;
    const __half* Mh  = (const __half*)(ws + WS_MH);

    const int wid  = threadIdx.x >> 6, lane = threadIdx.x & 63;
    const int rib  = wid >> 1;
    const int h    = wid & 1;
    const int b    = blockIdx.x * 2 + rib;
    const bool L50 = (lane < 50);

    const int sidx = inputs[b * L_ + (L50 ? lane : 0)];
    const int off  = L50 ? 4 * lane : 0;
    const int lbase = 25 * h;

    float a0 = 0.f, a1 = 0.f, a2 = 0.f, a3 = 0.f;
    #pragma unroll 5
    for (int j = 0; j < 25; ++j) {
        const int row = __shfl(sidx, lbase + j, 64);
        float4 x = *(const float4*)(emb + (size_t)row * D_ + off);
        a0 += x.x; a1 += x.y; a2 += x.z; a3 += x.w;
    }
    if (L50) {
        xav[rib][h][4 * lane + 0] = a0;
        xav[rib][h][4 * lane + 1] = a1;
        xav[rib][h][4 * lane + 2] = a2;
        xav[rib][h][4 * lane + 3] = a3;
    }
    __syncthreads();
    unsigned xu0 = 0, xu1 = 0;
    if (L50) {
        const float inv = 1.0f / (float)L_;
        float f0 = (xav[rib][0][4*lane+0] + xav[rib][1][4*lane+0]) * inv;
        float f1 = (xav[rib][0][4*lane+1] + xav[rib][1][4*lane+1]) * inv;
        float f2 = (xav[rib][0][4*lane+2] + xav[rib][1][4*lane+2]) * inv;
        float f3 = (xav[rib][0][4*lane+3] + xav[rib][1][4*lane+3]) * inv;
        xu0 = packh2(f0, f1);
        xu1 = packh2(f2, f3);
    }

    {
        float w0 = 0.f, w1 = 0.f;
        const int mr = 100 * h + 2 * (L50 ? lane : 0);
        const __half* m0 = Mh + (size_t)(mr + 0) * D_;
        const __half* m1 = Mh + (size_t)(mr + 1) * D_;
        #pragma unroll 5
        for (int c = 0; c < 25; ++c) {
            unsigned xa = __shfl(xu0, 2 * c,     64);
            unsigned xb = __shfl(xu1, 2 * c,     64);
            unsigned xc = __shfl(xu0, 2 * c + 1, 64);
            unsigned xd = __shfl(xu1, 2 * c + 1, 64);
            uint4 q0 = *(const uint4*)(m0 + 8 * c);
            uint4 q1 = *(const uint4*)(m1 + 8 * c);
            w0 = fd2(q0.x, xa, w0); w0 = fd2(q0.y, xb, w0); w0 = fd2(q0.z, xc, w0); w0 = fd2(q0.w, xd, w0);
            w1 = fd2(q1.x, xa, w1); w1 = fd2(q1.y, xb, w1); w1 = fd2(q1.z, xc, w1); w1 = fd2(q1.w, xd, w1);
        }
        if (L50) { vsh[rib][mr] = w0; vsh[rib][mr + 1] = w1; }
    }
    __syncthreads();
    float v0 = 0.f, v1 = 0.f, v2 = 0.f, v3 = 0.f;
    if (L50) {
        v0 = vsh[rib][4 * lane + 0];
        v1 = vsh[rib][4 * lane + 1];
        v2 = vsh[rib][4 * lane + 2];
        v3 = vsh[rib][4 * lane + 3];
    }

    float m = -INFINITY, ssum = 0.f;
    float e0 = 0.f, e1 = 0.f, e2 = 0.f, e3 = 0.f;
    {
        float4 bufA[5], bufB[5];
        auto LOADC = [&](float4* xb, int base) {
            #pragma unroll
            for (int j = 0; j < 5; ++j) {
                const int r = __shfl(sidx, lbase + base + j, 64);
                xb[j] = *(const float4*)(emb + (size_t)r * D_ + off);
            }
        };
        auto PROC = [&](const float4* xb) {
            #pragma unroll
            for (int j = 0; j < 5; ++j) {
                const float4 x = xb[j];
                float part = L50 ? (x.x * v0 + x.y * v1 + x.z * v2 + x.w * v3) : 0.f;
                const float s = bfly_sum(part);
                if (s > m) {
                    const float r = expf(m - s);
                    ssum *= r; e0 *= r; e1 *= r; e2 *= r; e3 *= r;
                    m = s;
                }
                const float w = expf(s - m);
                ssum += w;
                e0 = fmaf(w, x.x, e0); e1 = fmaf(w, x.y, e1);
                e2 = fmaf(w, x.z, e2); e3 = fmaf(w, x.w, e3);
            }
        };
        LOADC(bufA, 0);
        LOADC(bufB, 5);  PROC(bufA);
        LOADC(bufA, 10); PROC(bufB);
        LOADC(bufB, 15); PROC(bufA);
        LOADC(bufA, 20); PROC(bufB);
        PROC(bufA);
    }
    if (L50) {
        ench[rib][h][4 * lane + 0] = e0;
        ench[rib][h][4 * lane + 1] = e1;
        ench[rib][h][4 * lane + 2] = e2;
        ench[rib][h][4 * lane + 3] = e3;
    }
    if (lane == 0) { msh[rib][h][0] = m; msh[rib][h][1] = ssum; }
    __syncthreads();

    {
        const float mo  = msh[rib][1 - h][0];
        const float sso = msh[rib][1 - h][1];
        const float M   = fmaxf(m, mo);
        const float wA  = expf(m - M);
        const float wB  = expf(mo - M);
        const float st  = ssum * wA + sso * wB;
        const float rs  = 1.0f / st;
        if (L50) {
            e0 = (e0 * wA + ench[rib][1 - h][4 * lane + 0] * wB) * rs;
            e1 = (e1 * wA + ench[rib][1 - h][4 * lane + 1] * wB) * rs;
            e2 = (e2 * wA + ench[rib][1 - h][4 * lane + 2] * wB) * rs;
            e3 = (e3 * wA + ench[rib][1 - h][4 * lane + 3] * wB) * rs;
        } else {
            e0 = e1 = e2 = e3 = 0.f;
        }
    }

    const float n2 = bfly_sum(e0 * e0 + e1 * e1 + e2 * e2 + e3 * e3);
    const float un = fmaxf(sqrtf(n2), 1e-15f);
    const float pn = fminf(tanhf(un), 1.0f - 1e-5f);
    const float ps = pn / un;
    const float x2 = pn * pn;
    const float p0 = e0 * ps, p1 = e1 * ps, p2 = e2 * ps, p3 = e3 * ps;

    float kd = 0.f;
    #pragma unroll
    for (int a = 0; a < A_; ++a) {
        float4 k = *(const float4*)(kle + a * D_ + off);
        float part = L50 ? (p0 * k.x + p1 * k.y + p2 * k.z + p3 * k.w) : 0.f;
        float d = bfly_sum(part);
        if (lane == a) kd = d;
    }

    float px = 0.f, lfv = 0.f;
    if (lane < A_) {
        const float yy  = y2[lane];
        lfv = lf[lane];
        const float dot = kd * (1.0f + yy) * 0.5f;
        const float c1 = 1.0f - 2.0f * dot + yy;
        const float c2 = 1.0f - x2;
        const float num2 = c1 * c1 * x2 - 2.0f * c1 * c2 * dot + c2 * c2 * yy;
        const float den  = fmaxf(1.0f - 2.0f * dot + x2 * yy, 1e-15f);
        const float nma  = sqrtf(fmaxf(num2, 0.f)) / den;
        const float z    = fminf(nma, 1.0f - 1e-7f);
        const float dist = logf((1.0f + z) / (1.0f - z));
        px = expf(-dist * dist - 0.05f);
    }
    const float se = bfly_sum16(px);
    const float sp = bfly_sum16(lfv * px);
    float pev = 0.f;
    if (lane < A_) {
        pev = lfv * px / sp;
        if (h == 0) {
            out[B_ * D_ + b * A_ + lane] = pev;
            out[B_ * D_ + B_ * A_ + b * A_ + lane] = px / se;
        }
    }

    float k0 = 0.f, k1 = 0.f, k2 = 0.f, k3 = 0.f;
    #pragma unroll
    for (int a = 0; a < A_; ++a) {
        const float w = __shfl(pev, a, 64);
        float4 k = *(const float4*)(kle + a * D_ + off);
        k0 = fmaf(w, k.x, k0); k1 = fmaf(w, k.y, k1);
        k2 = fmaf(w, k.z, k2); k3 = fmaf(w, k.w, k3);
    }
    if (!L50) { k0 = k1 = k2 = k3 = 0.f; }
    const float n2k = bfly_sum(k0 * k0 + k1 * k1 + k2 * k2 + k3 * k3);
    const float denom = 1.0f + sqrtf(fmaxf(1.0f - n2k, 0.f));
    const float r2 = n2k / (denom * denom);
    const float rn = fmaxf(sqrtf(r2), 1e-15f);
    const float z2 = fminf(rn, 1.0f - 1e-7f);
    const float fac = 0.5f * logf((1.0f + z2) / (1.0f - z2)) / rn;
    if (L50 && h == 0) {
        float4 o = make_float4(fac * k0 / denom, fac * k1 / denom,
                               fac * k2 / denom, fac * k3 / denom);
        *(float4*)(out + (size_t)b * D_ + 4 * lane) = o;
    }
}

// ================= fallback f32 path (R4, proven) =================
#define G_R 8
__global__ __launch_bounds__(512) void gather_gemm(
    const int* __restrict__ inputs, const float* __restrict__ emb,
    const float* __restrict__ M, float* __restrict__ ws)
{
    __shared__ __align__(16) float xs[G_R][D_ + 4];
    __shared__ int sidx[G_R][L_];
    float* v = ws + WS_V;
    const int b0 = blockIdx.x * G_R;
    const int t = threadIdx.x;
    const int wave = t >> 6, lane = t & 63;

    for (int p = t; p < G_R * L_; p += 512) sidx[p / L_][p % L_] = inputs[b0 * L_ + p];
    __syncthreads();

    if (lane < D_ / 4) {
        float ax = 0.f, ay = 0.f, az = 0.f, aw = 0.f;
        #pragma unroll
        for (int l = 0; l < L_; ++l) {
            const float4 vv = ((const float4*)(emb + (size_t)sidx[wave][l] * D_))[lane];
            ax += vv.x; ay += vv.y; az += vv.z; aw += vv.w;
        }
        const float inv = 1.0f / (float)L_;
        ((float4*)xs[wave])[lane] = make_float4(ax * inv, ay * inv, az * inv, aw * inv);
    }
    __syncthreads();

    const int r = t & 7, dg = t >> 3;
    const float4* xr4 = (const float4*)xs[r];
    #pragma unroll
    for (int k = 0; k < 4; ++k) {
        const int d = dg + 64 * k;
        if (d < D_) {
            const float4* Mr4 = (const float4*)(M + d * D_);
            float acc = 0.f;
            #pragma unroll
            for (int e = 0; e < D_ / 4; ++e) {
                float4 m4 = Mr4[e], x4 = xr4[e];
                acc += m4.x * x4.x + m4.y * x4.y + m4.z * x4.z + m4.w * x4.w;
            }
            v[(size_t)(b0 + r) * D_ + d] = acc;
        }
    }
}

__global__ __launch_bounds__(512, 8) void fused_main(
    const int*   __restrict__ inputs,
    const float* __restrict__ emb,
    const float* __restrict__ ws,
    float* __restrict__ out)
{
    __shared__ __align__(16) float x[L_][D_];
    __shared__ float attn[L_];
    __shared__ int   sidx[L_];
    __shared__ float red[8];
    __shared__ float sums[2];

    const float* hyp = ws + WS_HYP;
    const float* kle = ws + WS_KLE;
    const float* y2  = ws + WS_Y2;
    const float* lf  = ws + WS_LF;
    const float* vg  = ws + WS_V;

    const int b = blockIdx.x;
    const int t = threadIdx.x;
    const int wave = t >> 6, lane = t & 63;

    float vr0 = vg[(size_t)b * D_ + lane];
    float vr1 = vg[(size_t)b * D_ + lane + 64];
    float vr2 = vg[(size_t)b * D_ + lane + 128];
    float vr3 = (lane < D_ - 192) ? vg[(size_t)b * D_ + lane + 192] : 0.f;

    if (t < L_) sidx[t] = inputs[b * L_ + t];
    __syncthreads();

    {
        const int DQ = D_ / 4;
        const int p0 = t, p1 = t + 512, p2 = t + 1024, p3 = t + 1536, p4 = t + 2048;
        const bool has4 = (p4 < L_ * DQ);
        float4 a0 = ((const float4*)(emb + (size_t)sidx[p0 / DQ] * D_))[p0 % DQ];
        float4 a1 = ((const float4*)(emb + (size_t)sidx[p1 / DQ] * D_))[p1 % DQ];
        float4 a2 = ((const float4*)(emb + (size_t)sidx[p2 / DQ] * D_))[p2 % DQ];
        float4 a3 = ((const float4*)(emb + (size_t)sidx[p3 / DQ] * D_))[p3 % DQ];
        float4 a4;
        if (has4) a4 = ((const float4*)(emb + (size_t)sidx[p4 / DQ] * D_))[p4 % DQ];
        ((float4*)x[p0 / DQ])[p0 % DQ] = a0;
        ((float4*)x[p1 / DQ])[p1 % DQ] = a1;
        ((float4*)x[p2 / DQ])[p2 % DQ] = a2;
        ((float4*)x[p3 / DQ])[p3 % DQ] = a3;
        if (has4) ((float4*)x[p4 / DQ])[p4 % DQ] = a4;
    }
    __syncthreads();

    for (int l = wave; l < L_; l += 8) {
        float s = x[l][lane] * vr0 + x[l][lane + 64] * vr1 + x[l][lane + 128] * vr2;
        if (lane < D_ - 192) s += x[l][lane + 192] * vr3;
        s = wave_reduce_sum(s);
        if (lane == 0) attn[l] = s;
    }
    __syncthreads();

    if (wave == 0) {
        float scv = (lane < L_) ? attn[lane] : -INFINITY;
        float m = scv;
        #pragma unroll
        for (int off = 32; off > 0; off >>= 1) m = fmaxf(m, __shfl_xor(m, off, 64));
        float e = (lane < L_) ? expf(scv - m) : 0.f;
        float ss = e;
        #pragma unroll
        for (int off = 32; off > 0; off >>= 1) ss += __shfl_xor(ss, off, 64);
        if (lane < L_) attn[lane] = e / ss;
    }
    __syncthreads();

    float encv = 0.f;
    if (t < D_) {
        #pragma unroll 10
        for (int l = 0; l < L_; ++l) encv += attn[l] * x[l][t];
    }

    float n2 = block_reduce_512((t < D_) ? encv * encv : 0.f, red);
    const float maxn = 1.0f - 1e-5f;
    float un = fmaxf(sqrtf(n2), 1e-15f);
    float pn = fminf(tanhf(un), maxn);
    float ps = pn / un;
    float x2 = pn * pn;
    float* pvec  = &x[0][0];
    float* dotpq = &x[1][0];
    float* pexp  = &x[1][16];
    float* pe    = &x[1][32];
    if (t < D_) pvec[t] = encv * ps;
    __syncthreads();

    for (int a = wave; a < A_; a += 8) {
        const float* ha = hyp + a * D_;
        float s = ha[lane] * pvec[lane] + ha[lane + 64] * pvec[lane + 64]
                + ha[lane + 128] * pvec[lane + 128];
        if (lane < D_ - 192) s += ha[lane + 192] * pvec[lane + 192];
        s = wave_reduce_sum(s);
        if (lane == 0) dotpq[a] = s;
    }
    __syncthreads();

    if (t < A_) {
        float dot = dotpq[t];
        float yy  = y2[t];
        float c1 = 1.0f - 2.0f * dot + yy;
        float c2 = 1.0f - x2;
        float num2 = c1 * c1 * x2 - 2.0f * c1 * c2 * dot + c2 * c2 * yy;
        float den  = fmaxf(1.0f - 2.0f * dot + x2 * yy, 1e-15f);
        float nma  = sqrtf(fmaxf(num2, 0.f)) / den;
        float z    = fminf(nma, 1.0f - 1e-7f);
        float dist = logf((1.0f + z) / (1.0f - z));
        pexp[t] = expf(-dist * dist - 0.05f);
    }
    __syncthreads();
    if (t == 0) {
        float se = 0.f, sp = 0.f;
        for (int a = 0; a < A_; ++a) { se += pexp[a]; sp += lf[a] * pexp[a]; }
        sums[0] = 1.0f / se;
        sums[1] = 1.0f / sp;
    }
    __syncthreads();
    if (t < A_) {
        float ap  = pexp[t] * sums[0];
        float pev = lf[t] * pexp[t] * sums[1];
        pe[t] = pev;
        out[B_ * D_ + b * A_ + t] = pev;
        out[B_ * D_ + B_ * A_ + b * A_ + t] = ap;
    }
    __syncthreads();

    float ko = 0.f;
    if (t < D_) {
        #pragma unroll
        for (int a = 0; a < A_; ++a) ko += kle[a * D_ + t] * pe[a];
    }
    float n2k = block_reduce_512((t < D_) ? ko * ko : 0.f, red);
    if (t < D_) {
        float denom = 1.0f + sqrtf(fmaxf(1.0f - n2k, 0.f));
        float rv = ko / denom;
        float r2 = n2k / (denom * denom);
        float rn = fmaxf(sqrtf(r2), 1e-15f);
        float z  = fminf(rn, 1.0f - 1e-7f);
        float fac = (0.5f * logf((1.0f + z) / (1.0f - z))) / rn;
        out[b * D_ + t] = fac * rv;
    }
}

extern "C" void kernel_launch(void* const* d_in, const int* in_sizes, int n_in,
                              void* d_out, int out_size, void* d_ws, size_t ws_size,
                              hipStream_t stream) {
    (void)in_sizes; (void)n_in; (void)out_size;
    const int*   inputs = (const int*)  d_in[0];
    const float* emb    = (const float*)d_in[1];
    const float* M      = (const float*)d_in[2];
    const float* a_emb  = (const float*)d_in[3];
    const float* seed_w = (const float*)d_in[4];
    float* out = (float*)d_out;
    float* ws  = (float*)d_ws;

    const size_t need_mh   = (size_t)(WS_MH + 20000) * sizeof(float);
    const size_t need_embh = (size_t)(WS_EMBH + EMBH_FLOATS) * sizeof(float);
    if (ws_size >= need_embh) {
        __half* Mh   = (__half*)(ws + WS_MH);
        __half* embh = (__half*)(ws + WS_EMBH);
        prep_all<<<2049, 256, 0, stream>>>(a_emb, seed_w, emb, M, ws, embh, Mh);
        fused_wave2_h<<<B_ / 2, 256, 0, stream>>>(inputs, ws, out);
    } else if (ws_size >= need_mh) {
        precompute_anchors<<<1, 256, 0, stream>>>(a_emb, seed_w, ws);
        __half* Mh = (__half*)(ws + WS_MH);
        convert_M<<<(D_ * D_ + 255) / 256, 256, 0, stream>>>(M, Mh);
        fused_wave2<<<B_ / 2, 256, 0, stream>>>(inputs, emb, ws, out);
    } else {
        precompute_anchors<<<1, 256, 0, stream>>>(a_emb, seed_w, ws);
        gather_gemm<<<B_ / G_R, 512, 0, stream>>>(inputs, emb, M, ws);
        fused_main<<<B_, 512, 0, stream>>>(inputs, emb, ws, out);
    }
}

// Round 19
// 106.487 us; speedup vs baseline: 1.1373x; 1.1373x over previous
//
#include <hip/hip_runtime.h>
#include <hip/hip_fp16.h>
#include <math.h>

#define B_ 4096
#define L_ 50
#define D_ 200
#define A_ 14
#define S_ 30

// ws layout (floats)
#define WS_HYP   0
#define WS_KLE   (A_ * D_)
#define WS_Y2    (2 * A_ * D_)
#define WS_LF    (WS_Y2 + A_)
#define WS_MH    8192                      // Mh: 40000 halves = 20000 floats
#define WS_EMBH  (WS_MH + 20000)           // embh: 10M halves = 5M floats
#define EMBH_FLOATS ((50000 * D_) / 2)
#define WS_V     8192                      // fallback f32 path only

// ---------- helpers ----------
__device__ __forceinline__ float wave_reduce_sum(float v) {
    #pragma unroll
    for (int off = 32; off > 0; off >>= 1) v += __shfl_down(v, off, 64);
    return v;
}
__device__ __forceinline__ float bfly_sum(float v) {
    #pragma unroll
    for (int m = 32; m > 0; m >>= 1) v += __shfl_xor(v, m, 64);
    return v;
}
__device__ __forceinline__ float bfly_max(float v) {
    #pragma unroll
    for (int m = 32; m > 0; m >>= 1) v = fmaxf(v, __shfl_xor(v, m, 64));
    return v;
}
__device__ __forceinline__ float bfly_sum16(float v) {
    #pragma unroll
    for (int m = 8; m > 0; m >>= 1) v += __shfl_xor(v, m, 64);
    return v;
}
__device__ __forceinline__ float block_reduce_512(float val, volatile float* red) {
    __syncthreads();
    val = wave_reduce_sum(val);
    if ((threadIdx.x & 63) == 0) red[threadIdx.x >> 6] = val;
    __syncthreads();
    float s = 0.f;
    #pragma unroll
    for (int i = 0; i < 8; ++i) s += red[i];
    return s;
}

typedef _Float16 h2v __attribute__((ext_vector_type(2)));
__device__ __forceinline__ float fd2(unsigned a, unsigned b, float c) {
#if __has_builtin(__builtin_amdgcn_fdot2)
    return __builtin_amdgcn_fdot2(__builtin_bit_cast(h2v, a),
                                  __builtin_bit_cast(h2v, b), c, false);
#else
    __half2 ha = __builtin_bit_cast(__half2, a), hb = __builtin_bit_cast(__half2, b);
    float2 fa = __half22float2(ha), fb = __half22float2(hb);
    return fmaf(fa.x, fb.x, fmaf(fa.y, fb.y, c));
#endif
}
__device__ __forceinline__ unsigned packh2(float a, float b) {
    __half2 h = __floats2half2_rn(a, b);
    return __builtin_bit_cast(unsigned, h);
}

// ---------- device body: anchor precompute (runs in one block) ----------
__device__ void anchors_body(const float* __restrict__ a_emb,
                             const float* __restrict__ seed_w,
                             float* __restrict__ ws)
{
    __shared__ float u[A_][D_];
    __shared__ float nrm2[A_];
    const int t = threadIdx.x;
    const int wave = t >> 6, lane = t & 63;

    for (int d = t; d < D_; d += 256) {
        for (int a = 0; a < A_; ++a) {
            float acc = 0.f;
            #pragma unroll 5
            for (int s = 0; s < S_; ++s)
                acc += a_emb[(a * S_ + s) * D_ + d] * seed_w[a * S_ + s];
            u[a][d] = acc;
        }
    }
    __syncthreads();

    for (int a = wave; a < A_; a += 4) {
        float s = 0.f;
        for (int d = lane; d < D_; d += 64) s += u[a][d] * u[a][d];
        s = wave_reduce_sum(s);
        if (lane == 0) nrm2[a] = s;
    }
    __syncthreads();

    float* hyp = ws + WS_HYP;
    float* kle = ws + WS_KLE;
    float* y2  = ws + WS_Y2;
    float* lf  = ws + WS_LF;
    const float maxn = 1.0f - 1e-5f;

    for (int a = 0; a < A_; ++a) {
        float un = fmaxf(sqrtf(nrm2[a]), 1e-15f);
        float th = tanhf(un);
        float pn = fminf(th, maxn);
        float s  = pn / un;
        float py2 = pn * pn;
        float kscale = 2.0f / (1.0f + py2);
        float k2 = py2 * kscale * kscale;
        if (t == 0) {
            y2[a] = py2;
            lf[a] = 1.0f / sqrtf(fmaxf(1.0f - k2, 1e-7f));
        }
        for (int d = t; d < D_; d += 256) {
            float h = u[a][d] * s;
            hyp[a * D_ + d] = h;
            kle[a * D_ + d] = h * kscale;
        }
    }
}

// ---------- kernel 0 (merged): anchors (block 0) + emb/M f32->f16 convert ----------
__global__ __launch_bounds__(256) void prep_all(
    const float* __restrict__ a_emb, const float* __restrict__ seed_w,
    const float* __restrict__ emb,   const float* __restrict__ M,
    float* __restrict__ ws, __half* __restrict__ embh, __half* __restrict__ Mh)
{
    if (blockIdx.x == 0) {
        anchors_body(a_emb, seed_w, ws);
        return;
    }
    const int nb = gridDim.x - 1;              // converter blocks
    const int cb = blockIdx.x - 1;
    const int n4e = (50000 * D_) / 4;          // 2,500,000
    const int n4m = (D_ * D_) / 4;             // 10,000
    for (int i = cb * 256 + threadIdx.x; i < n4e + n4m; i += nb * 256) {
        if (i < n4e) {
            float4 v = ((const float4*)emb)[i];
            uint2 u; u.x = packh2(v.x, v.y); u.y = packh2(v.z, v.w);
            ((uint2*)embh)[i] = u;
        } else {
            const int j = i - n4e;
            float4 v = ((const float4*)M)[j];
            uint2 u; u.x = packh2(v.x, v.y); u.y = packh2(v.z, v.w);
            ((uint2*)Mh)[j] = u;
        }
    }
}

// ---------- standalone anchors (fallback paths) ----------
__global__ __launch_bounds__(256) void precompute_anchors(
    const float* __restrict__ a_emb, const float* __restrict__ seed_w,
    float* __restrict__ ws)
{
    anchors_body(a_emb, seed_w, ws);
}

// ---------- kernel (primary): R12 structure, fp16 loads (R17-proven, lb 256,6) ----------
__global__ __launch_bounds__(256, 6) void fused_wave2_h(
    const int*   __restrict__ inputs,
    const float* __restrict__ ws,
    float* __restrict__ out)
{
    __shared__ float xav[2][2][D_];
    __shared__ float vsh[2][D_];
    __shared__ float ench[2][2][D_];
    __shared__ float msh[2][2][2];

    const float*  kle  = ws + WS_KLE;
    const float*  y2   = ws + WS_Y2;
    const float*  lf   = ws + WS_LF;
    const __half* Mh   = (const __half*)(ws + WS_MH);
    const __half* embh = (const __half*)(ws + WS_EMBH);

    const int wid  = threadIdx.x >> 6, lane = threadIdx.x & 63;
    const int rib  = wid >> 1;
    const int h    = wid & 1;
    const int b    = blockIdx.x * 2 + rib;
    const bool L50 = (lane < 50);

    const int sidx = inputs[b * L_ + (L50 ? lane : 0)];
    const int offh = L50 ? 4 * lane : 0;        // half-units
    const int lbase = 25 * h;

    // ---- P1: x_avg partials over this wave's 25 rows (fp16 loads) ----
    float a0 = 0.f, a1 = 0.f, a2 = 0.f, a3 = 0.f;
    #pragma unroll 5
    for (int j = 0; j < 25; ++j) {
        const int row = __shfl(sidx, lbase + j, 64);
        uint2 u = *(const uint2*)(embh + (size_t)row * D_ + offh);
        float2 f0 = __half22float2(__builtin_bit_cast(__half2, u.x));
        float2 f1 = __half22float2(__builtin_bit_cast(__half2, u.y));
        a0 += f0.x; a1 += f0.y; a2 += f1.x; a3 += f1.y;
    }
    if (L50) {
        xav[rib][h][4 * lane + 0] = a0;
        xav[rib][h][4 * lane + 1] = a1;
        xav[rib][h][4 * lane + 2] = a2;
        xav[rib][h][4 * lane + 3] = a3;
    }
    __syncthreads();
    unsigned xu0 = 0, xu1 = 0;
    if (L50) {
        const float inv = 1.0f / (float)L_;
        float f0 = (xav[rib][0][4*lane+0] + xav[rib][1][4*lane+0]) * inv;
        float f1 = (xav[rib][0][4*lane+1] + xav[rib][1][4*lane+1]) * inv;
        float f2 = (xav[rib][0][4*lane+2] + xav[rib][1][4*lane+2]) * inv;
        float f3 = (xav[rib][0][4*lane+3] + xav[rib][1][4*lane+3]) * inv;
        xu0 = packh2(f0, f1);
        xu1 = packh2(f2, f3);
    }

    // ---- P2: v for dims [100h, 100h+100): lane owns 2 M rows (fp16, fdot2) ----
    {
        float w0 = 0.f, w1 = 0.f;
        const int mr = 100 * h + 2 * (L50 ? lane : 0);
        const __half* m0 = Mh + (size_t)(mr + 0) * D_;
        const __half* m1 = Mh + (size_t)(mr + 1) * D_;
        #pragma unroll 5
        for (int c = 0; c < 25; ++c) {
            unsigned xa = __shfl(xu0, 2 * c,     64);
            unsigned xb = __shfl(xu1, 2 * c,     64);
            unsigned xc = __shfl(xu0, 2 * c + 1, 64);
            unsigned xd = __shfl(xu1, 2 * c + 1, 64);
            uint4 q0 = *(const uint4*)(m0 + 8 * c);
            uint4 q1 = *(const uint4*)(m1 + 8 * c);
            w0 = fd2(q0.x, xa, w0); w0 = fd2(q0.y, xb, w0); w0 = fd2(q0.z, xc, w0); w0 = fd2(q0.w, xd, w0);
            w1 = fd2(q1.x, xa, w1); w1 = fd2(q1.y, xb, w1); w1 = fd2(q1.z, xc, w1); w1 = fd2(q1.w, xd, w1);
        }
        if (L50) { vsh[rib][mr] = w0; vsh[rib][mr + 1] = w1; }
    }
    __syncthreads();
    float v0 = 0.f, v1 = 0.f, v2 = 0.f, v3 = 0.f;
    if (L50) {
        v0 = vsh[rib][4 * lane + 0];
        v1 = vsh[rib][4 * lane + 1];
        v2 = vsh[rib][4 * lane + 2];
        v3 = vsh[rib][4 * lane + 3];
    }

    // ---- P3: flash-online over this wave's 25 rows, 5-deep dbuf (fp16) ----
    float m = -INFINITY, ssum = 0.f;
    float e0 = 0.f, e1 = 0.f, e2 = 0.f, e3 = 0.f;
    {
        uint2 bufA[5], bufB[5];
        auto LOADC = [&](uint2* xb, int base) {
            #pragma unroll
            for (int j = 0; j < 5; ++j) {
                const int r = __shfl(sidx, lbase + base + j, 64);
                xb[j] = *(const uint2*)(embh + (size_t)r * D_ + offh);
            }
        };
        auto PROC = [&](const uint2* xb) {
            #pragma unroll
            for (int j = 0; j < 5; ++j) {
                float2 f0 = __half22float2(__builtin_bit_cast(__half2, xb[j].x));
                float2 f1 = __half22float2(__builtin_bit_cast(__half2, xb[j].y));
                float part = L50 ? (f0.x * v0 + f0.y * v1 + f1.x * v2 + f1.y * v3) : 0.f;
                const float s = bfly_sum(part);
                if (s > m) {
                    const float r = expf(m - s);
                    ssum *= r; e0 *= r; e1 *= r; e2 *= r; e3 *= r;
                    m = s;
                }
                const float w = expf(s - m);
                ssum += w;
                e0 = fmaf(w, f0.x, e0); e1 = fmaf(w, f0.y, e1);
                e2 = fmaf(w, f1.x, e2); e3 = fmaf(w, f1.y, e3);
            }
        };
        LOADC(bufA, 0);
        LOADC(bufB, 5);  PROC(bufA);
        LOADC(bufA, 10); PROC(bufB);
        LOADC(bufB, 15); PROC(bufA);
        LOADC(bufA, 20); PROC(bufB);
        PROC(bufA);
    }
    if (L50) {
        ench[rib][h][4 * lane + 0] = e0;
        ench[rib][h][4 * lane + 1] = e1;
        ench[rib][h][4 * lane + 2] = e2;
        ench[rib][h][4 * lane + 3] = e3;
    }
    if (lane == 0) { msh[rib][h][0] = m; msh[rib][h][1] = ssum; }
    __syncthreads();

    // ---- merge two flash states ----
    {
        const float mo  = msh[rib][1 - h][0];
        const float sso = msh[rib][1 - h][1];
        const float M   = fmaxf(m, mo);
        const float wA  = expf(m - M);
        const float wB  = expf(mo - M);
        const float st  = ssum * wA + sso * wB;
        const float rs  = 1.0f / st;
        if (L50) {
            e0 = (e0 * wA + ench[rib][1 - h][4 * lane + 0] * wB) * rs;
            e1 = (e1 * wA + ench[rib][1 - h][4 * lane + 1] * wB) * rs;
            e2 = (e2 * wA + ench[rib][1 - h][4 * lane + 2] * wB) * rs;
            e3 = (e3 * wA + ench[rib][1 - h][4 * lane + 3] * wB) * rs;
        } else {
            e0 = e1 = e2 = e3 = 0.f;
        }
    }

    // ---- P6: expmap0 + proj ----
    const float n2 = bfly_sum(e0 * e0 + e1 * e1 + e2 * e2 + e3 * e3);
    const float un = fmaxf(sqrtf(n2), 1e-15f);
    const float pn = fminf(tanhf(un), 1.0f - 1e-5f);
    const float ps = pn / un;
    const float x2 = pn * pn;
    const float p0 = e0 * ps, p1 = e1 * ps, p2 = e2 * ps, p3 = e3 * ps;
    const int koff = L50 ? 4 * lane : 0;

    // ---- P7: dot(p, kle_a); hyp-dot = kle-dot*(1+y2)/2 ----
    float kd = 0.f;
    #pragma unroll
    for (int a = 0; a < A_; ++a) {
        float4 k = *(const float4*)(kle + a * D_ + koff);
        float part = L50 ? (p0 * k.x + p1 * k.y + p2 * k.z + p3 * k.w) : 0.f;
        float d = bfly_sum(part);
        if (lane == a) kd = d;
    }

    // ---- P8: sqdist -> probs (lane a < 14) ----
    float px = 0.f, lfv = 0.f;
    if (lane < A_) {
        const float yy  = y2[lane];
        lfv = lf[lane];
        const float dot = kd * (1.0f + yy) * 0.5f;
        const float c1 = 1.0f - 2.0f * dot + yy;
        const float c2 = 1.0f - x2;
        const float num2 = c1 * c1 * x2 - 2.0f * c1 * c2 * dot + c2 * c2 * yy;
        const float den  = fmaxf(1.0f - 2.0f * dot + x2 * yy, 1e-15f);
        const float nma  = sqrtf(fmaxf(num2, 0.f)) / den;
        const float z    = fminf(nma, 1.0f - 1e-7f);
        const float dist = logf((1.0f + z) / (1.0f - z));
        px = expf(-dist * dist - 0.05f);
    }
    const float se = bfly_sum16(px);
    const float sp = bfly_sum16(lfv * px);
    float pev = 0.f;
    if (lane < A_) {
        pev = lfv * px / sp;
        if (h == 0) {
            out[B_ * D_ + b * A_ + lane] = pev;               // probs_expanded
            out[B_ * D_ + B_ * A_ + b * A_ + lane] = px / se; // a_probs
        }
    }

    // ---- P9: Klein barycenter -> klein_to -> logmap0 ----
    float k0 = 0.f, k1 = 0.f, k2 = 0.f, k3 = 0.f;
    #pragma unroll
    for (int a = 0; a < A_; ++a) {
        const float w = __shfl(pev, a, 64);
        float4 k = *(const float4*)(kle + a * D_ + koff);
        k0 = fmaf(w, k.x, k0); k1 = fmaf(w, k.y, k1);
        k2 = fmaf(w, k.z, k2); k3 = fmaf(w, k.w, k3);
    }
    if (!L50) { k0 = k1 = k2 = k3 = 0.f; }
    const float n2k = bfly_sum(k0 * k0 + k1 * k1 + k2 * k2 + k3 * k3);
    const float denom = 1.0f + sqrtf(fmaxf(1.0f - n2k, 0.f));
    const float r2 = n2k / (denom * denom);
    const float rn = fmaxf(sqrtf(r2), 1e-15f);
    const float z2 = fminf(rn, 1.0f - 1e-7f);
    const float fac = 0.5f * logf((1.0f + z2) / (1.0f - z2)) / rn;
    if (L50 && h == 0) {
        float4 o = make_float4(fac * k0 / denom, fac * k1 / denom,
                               fac * k2 / denom, fac * k3 / denom);
        *(float4*)(out + (size_t)b * D_ + 4 * lane) = o;
    }
}

// ---------- mid-tier: R12 f32 two-pass (proven 79.7) ----------
__global__ __launch_bounds__(256) void convert_M(
    const float* __restrict__ M, __half* __restrict__ Mh)
{
    int i = blockIdx.x * 256 + threadIdx.x;
    if (i < D_ * D_) Mh[i] = __float2half(M[i]);
}

__global__ __launch_bounds__(256, 6) void fused_wave2(
    const int*   __restrict__ inputs,
    const float* __restrict__ emb,
    const float* __restrict__ ws,
    float* __restrict__ out)
{
    __shared__ float xav[2][2][D_];
    __shared__ float vsh[2][D_];
    __shared__ float ench[2][2][D_];
    __shared__ float msh[2][2][2];

    const float*  kle = ws + WS_KLE;
    const float*  y2  = ws + WS_Y2;
    const float*  lf  = ws + WS_LF;
    const __half* Mh  = (const __half*)(ws + WS_MH);

    const int wid  = threadIdx.x >> 6, lane = threadIdx.x & 63;
    const int rib  = wid >> 1;
    const int h    = wid & 1;
    const int b    = blockIdx.x * 2 + rib;
    const bool L50 = (lane < 50);

    const int sidx = inputs[b * L_ + (L50 ? lane : 0)];
    const int off  = L50 ? 4 * lane : 0;
    const int lbase = 25 * h;

    float a0 = 0.f, a1 = 0.f, a2 = 0.f, a3 = 0.f;
    #pragma unroll 5
    for (int j = 0; j < 25; ++j) {
        const int row = __shfl(sidx, lbase + j, 64);
        float4 x = *(const float4*)(emb + (size_t)row * D_ + off);
        a0 += x.x; a1 += x.y; a2 += x.z; a3 += x.w;
    }
    if (L50) {
        xav[rib][h][4 * lane + 0] = a0;
        xav[rib][h][4 * lane + 1] = a1;
        xav[rib][h][4 * lane + 2] = a2;
        xav[rib][h][4 * lane + 3] = a3;
    }
    __syncthreads();
    unsigned xu0 = 0, xu1 = 0;
    if (L50) {
        const float inv = 1.0f / (float)L_;
        float f0 = (xav[rib][0][4*lane+0] + xav[rib][1][4*lane+0]) * inv;
        float f1 = (xav[rib][0][4*lane+1] + xav[rib][1][4*lane+1]) * inv;
        float f2 = (xav[rib][0][4*lane+2] + xav[rib][1][4*lane+2]) * inv;
        float f3 = (xav[rib][0][4*lane+3] + xav[rib][1][4*lane+3]) * inv;
        xu0 = packh2(f0, f1);
        xu1 = packh2(f2, f3);
    }

    {
        float w0 = 0.f, w1 = 0.f;
        const int mr = 100 * h + 2 * (L50 ? lane : 0);
        const __half* m0 = Mh + (size_t)(mr + 0) * D_;
        const __half* m1 = Mh + (size_t)(mr + 1) * D_;
        #pragma unroll 5
        for (int c = 0; c < 25; ++c) {
            unsigned xa = __shfl(xu0, 2 * c,     64);
            unsigned xb = __shfl(xu1, 2 * c,     64);
            unsigned xc = __shfl(xu0, 2 * c + 1, 64);
            unsigned xd = __shfl(xu1, 2 * c + 1, 64);
            uint4 q0 = *(const uint4*)(m0 + 8 * c);
            uint4 q1 = *(const uint4*)(m1 + 8 * c);
            w0 = fd2(q0.x, xa, w0); w0 = fd2(q0.y, xb, w0); w0 = fd2(q0.z, xc, w0); w0 = fd2(q0.w, xd, w0);
            w1 = fd2(q1.x, xa, w1); w1 = fd2(q1.y, xb, w1); w1 = fd2(q1.z, xc, w1); w1 = fd2(q1.w, xd, w1);
        }
        if (L50) { vsh[rib][mr] = w0; vsh[rib][mr + 1] = w1; }
    }
    __syncthreads();
    float v0 = 0.f, v1 = 0.f, v2 = 0.f, v3 = 0.f;
    if (L50) {
        v0 = vsh[rib][4 * lane + 0];
        v1 = vsh[rib][4 * lane + 1];
        v2 = vsh[rib][4 * lane + 2];
        v3 = vsh[rib][4 * lane + 3];
    }

    float m = -INFINITY, ssum = 0.f;
    float e0 = 0.f, e1 = 0.f, e2 = 0.f, e3 = 0.f;
    {
        float4 bufA[5], bufB[5];
        auto LOADC = [&](float4* xb, int base) {
            #pragma unroll
            for (int j = 0; j < 5; ++j) {
                const int r = __shfl(sidx, lbase + base + j, 64);
                xb[j] = *(const float4*)(emb + (size_t)r * D_ + off);
            }
        };
        auto PROC = [&](const float4* xb) {
            #pragma unroll
            for (int j = 0; j < 5; ++j) {
                const float4 x = xb[j];
                float part = L50 ? (x.x * v0 + x.y * v1 + x.z * v2 + x.w * v3) : 0.f;
                const float s = bfly_sum(part);
                if (s > m) {
                    const float r = expf(m - s);
                    ssum *= r; e0 *= r; e1 *= r; e2 *= r; e3 *= r;
                    m = s;
                }
                const float w = expf(s - m);
                ssum += w;
                e0 = fmaf(w, x.x, e0); e1 = fmaf(w, x.y, e1);
                e2 = fmaf(w, x.z, e2); e3 = fmaf(w, x.w, e3);
            }
        };
        LOADC(bufA, 0);
        LOADC(bufB, 5);  PROC(bufA);
        LOADC(bufA, 10); PROC(bufB);
        LOADC(bufB, 15); PROC(bufA);
        LOADC(bufA, 20); PROC(bufB);
        PROC(bufA);
    }
    if (L50) {
        ench[rib][h][4 * lane + 0] = e0;
        ench[rib][h][4 * lane + 1] = e1;
        ench[rib][h][4 * lane + 2] = e2;
        ench[rib][h][4 * lane + 3] = e3;
    }
    if (lane == 0) { msh[rib][h][0] = m; msh[rib][h][1] = ssum; }
    __syncthreads();

    {
        const float mo  = msh[rib][1 - h][0];
        const float sso = msh[rib][1 - h][1];
        const float M   = fmaxf(m, mo);
        const float wA  = expf(m - M);
        const float wB  = expf(mo - M);
        const float st  = ssum * wA + sso * wB;
        const float rs  = 1.0f / st;
        if (L50) {
            e0 = (e0 * wA + ench[rib][1 - h][4 * lane + 0] * wB) * rs;
            e1 = (e1 * wA + ench[rib][1 - h][4 * lane + 1] * wB) * rs;
            e2 = (e2 * wA + ench[rib][1 - h][4 * lane + 2] * wB) * rs;
            e3 = (e3 * wA + ench[rib][1 - h][4 * lane + 3] * wB) * rs;
        } else {
            e0 = e1 = e2 = e3 = 0.f;
        }
    }

    const float n2 = bfly_sum(e0 * e0 + e1 * e1 + e2 * e2 + e3 * e3);
    const float un = fmaxf(sqrtf(n2), 1e-15f);
    const float pn = fminf(tanhf(un), 1.0f - 1e-5f);
    const float ps = pn / un;
    const float x2 = pn * pn;
    const float p0 = e0 * ps, p1 = e1 * ps, p2 = e2 * ps, p3 = e3 * ps;

    float kd = 0.f;
    #pragma unroll
    for (int a = 0; a < A_; ++a) {
        float4 k = *(const float4*)(kle + a * D_ + off);
        float part = L50 ? (p0 * k.x + p1 * k.y + p2 * k.z + p3 * k.w) : 0.f;
        float d = bfly_sum(part);
        if (lane == a) kd = d;
    }

    float px = 0.f, lfv = 0.f;
    if (lane < A_) {
        const float yy  = y2[lane];
        lfv = lf[lane];
        const float dot = kd * (1.0f + yy) * 0.5f;
        const float c1 = 1.0f - 2.0f * dot + yy;
        const float c2 = 1.0f - x2;
        const float num2 = c1 * c1 * x2 - 2.0f * c1 * c2 * dot + c2 * c2 * yy;
        const float den  = fmaxf(1.0f - 2.0f * dot + x2 * yy, 1e-15f);
        const float nma  = sqrtf(fmaxf(num2, 0.f)) / den;
        const float z    = fminf(nma, 1.0f - 1e-7f);
        const float dist = logf((1.0f + z) / (1.0f - z));
        px = expf(-dist * dist - 0.05f);
    }
    const float se = bfly_sum16(px);
    const float sp = bfly_sum16(lfv * px);
    float pev = 0.f;
    if (lane < A_) {
        pev = lfv * px / sp;
        if (h == 0) {
            out[B_ * D_ + b * A_ + lane] = pev;
            out[B_ * D_ + B_ * A_ + b * A_ + lane] = px / se;
        }
    }

    float k0 = 0.f, k1 = 0.f, k2 = 0.f, k3 = 0.f;
    #pragma unroll
    for (int a = 0; a < A_; ++a) {
        const float w = __shfl(pev, a, 64);
        float4 k = *(const float4*)(kle + a * D_ + off);
        k0 = fmaf(w, k.x, k0); k1 = fmaf(w, k.y, k1);
        k2 = fmaf(w, k.z, k2); k3 = fmaf(w, k.w, k3);
    }
    if (!L50) { k0 = k1 = k2 = k3 = 0.f; }
    const float n2k = bfly_sum(k0 * k0 + k1 * k1 + k2 * k2 + k3 * k3);
    const float denom = 1.0f + sqrtf(fmaxf(1.0f - n2k, 0.f));
    const float r2 = n2k / (denom * denom);
    const float rn = fmaxf(sqrtf(r2), 1e-15f);
    const float z2 = fminf(rn, 1.0f - 1e-7f);
    const float fac = 0.5f * logf((1.0f + z2) / (1.0f - z2)) / rn;
    if (L50 && h == 0) {
        float4 o = make_float4(fac * k0 / denom, fac * k1 / denom,
                               fac * k2 / denom, fac * k3 / denom);
        *(float4*)(out + (size_t)b * D_ + 4 * lane) = o;
    }
}

// ================= fallback f32 path (R4, proven) =================
#define G_R 8
__global__ __launch_bounds__(512) void gather_gemm(
    const int* __restrict__ inputs, const float* __restrict__ emb,
    const float* __restrict__ M, float* __restrict__ ws)
{
    __shared__ __align__(16) float xs[G_R][D_ + 4];
    __shared__ int sidx[G_R][L_];
    float* v = ws + WS_V;
    const int b0 = blockIdx.x * G_R;
    const int t = threadIdx.x;
    const int wave = t >> 6, lane = t & 63;

    for (int p = t; p < G_R * L_; p += 512) sidx[p / L_][p % L_] = inputs[b0 * L_ + p];
    __syncthreads();

    if (lane < D_ / 4) {
        float ax = 0.f, ay = 0.f, az = 0.f, aw = 0.f;
        #pragma unroll
        for (int l = 0; l < L_; ++l) {
            const float4 vv = ((const float4*)(emb + (size_t)sidx[wave][l] * D_))[lane];
            ax += vv.x; ay += vv.y; az += vv.z; aw += vv.w;
        }
        const float inv = 1.0f / (float)L_;
        ((float4*)xs[wave])[lane] = make_float4(ax * inv, ay * inv, az * inv, aw * inv);
    }
    __syncthreads();

    const int r = t & 7, dg = t >> 3;
    const float4* xr4 = (const float4*)xs[r];
    #pragma unroll
    for (int k = 0; k < 4; ++k) {
        const int d = dg + 64 * k;
        if (d < D_) {
            const float4* Mr4 = (const float4*)(M + d * D_);
            float acc = 0.f;
            #pragma unroll
            for (int e = 0; e < D_ / 4; ++e) {
                float4 m4 = Mr4[e], x4 = xr4[e];
                acc += m4.x * x4.x + m4.y * x4.y + m4.z * x4.z + m4.w * x4.w;
            }
            v[(size_t)(b0 + r) * D_ + d] = acc;
        }
    }
}

__global__ __launch_bounds__(512, 8) void fused_main(
    const int*   __restrict__ inputs,
    const float* __restrict__ emb,
    const float* __restrict__ ws,
    float* __restrict__ out)
{
    __shared__ __align__(16) float x[L_][D_];
    __shared__ float attn[L_];
    __shared__ int   sidx[L_];
    __shared__ float red[8];
    __shared__ float sums[2];

    const float* hyp = ws + WS_HYP;
    const float* kle = ws + WS_KLE;
    const float* y2  = ws + WS_Y2;
    const float* lf  = ws + WS_LF;
    const float* vg  = ws + WS_V;

    const int b = blockIdx.x;
    const int t = threadIdx.x;
    const int wave = t >> 6, lane = t & 63;

    float vr0 = vg[(size_t)b * D_ + lane];
    float vr1 = vg[(size_t)b * D_ + lane + 64];
    float vr2 = vg[(size_t)b * D_ + lane + 128];
    float vr3 = (lane < D_ - 192) ? vg[(size_t)b * D_ + lane + 192] : 0.f;

    if (t < L_) sidx[t] = inputs[b * L_ + t];
    __syncthreads();

    {
        const int DQ = D_ / 4;
        const int p0 = t, p1 = t + 512, p2 = t + 1024, p3 = t + 1536, p4 = t + 2048;
        const bool has4 = (p4 < L_ * DQ);
        float4 a0 = ((const float4*)(emb + (size_t)sidx[p0 / DQ] * D_))[p0 % DQ];
        float4 a1 = ((const float4*)(emb + (size_t)sidx[p1 / DQ] * D_))[p1 % DQ];
        float4 a2 = ((const float4*)(emb + (size_t)sidx[p2 / DQ] * D_))[p2 % DQ];
        float4 a3 = ((const float4*)(emb + (size_t)sidx[p3 / DQ] * D_))[p3 % DQ];
        float4 a4;
        if (has4) a4 = ((const float4*)(emb + (size_t)sidx[p4 / DQ] * D_))[p4 % DQ];
        ((float4*)x[p0 / DQ])[p0 % DQ] = a0;
        ((float4*)x[p1 / DQ])[p1 % DQ] = a1;
        ((float4*)x[p2 / DQ])[p2 % DQ] = a2;
        ((float4*)x[p3 / DQ])[p3 % DQ] = a3;
        if (has4) ((float4*)x[p4 / DQ])[p4 % DQ] = a4;
    }
    __syncthreads();

    for (int l = wave; l < L_; l += 8) {
        float s = x[l][lane] * vr0 + x[l][lane + 64] * vr1 + x[l][lane + 128] * vr2;
        if (lane < D_ - 192) s += x[l][lane + 192] * vr3;
        s = wave_reduce_sum(s);
        if (lane == 0) attn[l] = s;
    }
    __syncthreads();

    if (wave == 0) {
        float scv = (lane < L_) ? attn[lane] : -INFINITY;
        float m = scv;
        #pragma unroll
        for (int off = 32; off > 0; off >>= 1) m = fmaxf(m, __shfl_xor(m, off, 64));
        float e = (lane < L_) ? expf(scv - m) : 0.f;
        float ss = e;
        #pragma unroll
        for (int off = 32; off > 0; off >>= 1) ss += __shfl_xor(ss, off, 64);
        if (lane < L_) attn[lane] = e / ss;
    }
    __syncthreads();

    float encv = 0.f;
    if (t < D_) {
        #pragma unroll 10
        for (int l = 0; l < L_; ++l) encv += attn[l] * x[l][t];
    }

    float n2 = block_reduce_512((t < D_) ? encv * encv : 0.f, red);
    const float maxn = 1.0f - 1e-5f;
    float un = fmaxf(sqrtf(n2), 1e-15f);
    float pn = fminf(tanhf(un), maxn);
    float ps = pn / un;
    float x2 = pn * pn;
    float* pvec  = &x[0][0];
    float* dotpq = &x[1][0];
    float* pexp  = &x[1][16];
    float* pe    = &x[1][32];
    if (t < D_) pvec[t] = encv * ps;
    __syncthreads();

    for (int a = wave; a < A_; a += 8) {
        const float* ha = hyp + a * D_;
        float s = ha[lane] * pvec[lane] + ha[lane + 64] * pvec[lane + 64]
                + ha[lane + 128] * pvec[lane + 128];
        if (lane < D_ - 192) s += ha[lane + 192] * pvec[lane + 192];
        s = wave_reduce_sum(s);
        if (lane == 0) dotpq[a] = s;
    }
    __syncthreads();

    if (t < A_) {
        float dot = dotpq[t];
        float yy  = y2[t];
        float c1 = 1.0f - 2.0f * dot + yy;
        float c2 = 1.0f - x2;
        float num2 = c1 * c1 * x2 - 2.0f * c1 * c2 * dot + c2 * c2 * yy;
        float den  = fmaxf(1.0f - 2.0f * dot + x2 * yy, 1e-15f);
        float nma  = sqrtf(fmaxf(num2, 0.f)) / den;
        float z    = fminf(nma, 1.0f - 1e-7f);
        float dist = logf((1.0f + z) / (1.0f - z));
        pexp[t] = expf(-dist * dist - 0.05f);
    }
    __syncthreads();
    if (t == 0) {
        float se = 0.f, sp = 0.f;
        for (int a = 0; a < A_; ++a) { se += pexp[a]; sp += lf[a] * pexp[a]; }
        sums[0] = 1.0f / se;
        sums[1] = 1.0f / sp;
    }
    __syncthreads();
    if (t < A_) {
        float ap  = pexp[t] * sums[0];
        float pev = lf[t] * pexp[t] * sums[1];
        pe[t] = pev;
        out[B_ * D_ + b * A_ + t] = pev;
        out[B_ * D_ + B_ * A_ + b * A_ + t] = ap;
    }
    __syncthreads();

    float ko = 0.f;
    if (t < D_) {
        #pragma unroll
        for (int a = 0; a < A_; ++a) ko += kle[a * D_ + t] * pe[a];
    }
    float n2k = block_reduce_512((t < D_) ? ko * ko : 0.f, red);
    if (t < D_) {
        float denom = 1.0f + sqrtf(fmaxf(1.0f - n2k, 0.f));
        float rv = ko / denom;
        float r2 = n2k / (denom * denom);
        float rn = fmaxf(sqrtf(r2), 1e-15f);
        float z  = fminf(rn, 1.0f - 1e-7f);
        float fac = (0.5f * logf((1.0f + z) / (1.0f - z))) / rn;
        out[b * D_ + t] = fac * rv;
    }
}

extern "C" void kernel_launch(void* const* d_in, const int* in_sizes, int n_in,
                              void* d_out, int out_size, void* d_ws, size_t ws_size,
                              hipStream_t stream) {
    (void)in_sizes; (void)n_in; (void)out_size;
    const int*   inputs = (const int*)  d_in[0];
    const float* emb    = (const float*)d_in[1];
    const float* M      = (const float*)d_in[2];
    const float* a_emb  = (const float*)d_in[3];
    const float* seed_w = (const float*)d_in[4];
    float* out = (float*)d_out;
    float* ws  = (float*)d_ws;

    const size_t need_mh   = (size_t)(WS_MH + 20000) * sizeof(float);
    const size_t need_embh = (size_t)(WS_EMBH + EMBH_FLOATS) * sizeof(float);
    if (ws_size >= need_embh) {
        __half* Mh   = (__half*)(ws + WS_MH);
        __half* embh = (__half*)(ws + WS_EMBH);
        prep_all<<<2049, 256, 0, stream>>>(a_emb, seed_w, emb, M, ws, embh, Mh);
        fused_wave2_h<<<B_ / 2, 256, 0, stream>>>(inputs, ws, out);
    } else if (ws_size >= need_mh) {
        precompute_anchors<<<1, 256, 0, stream>>>(a_emb, seed_w, ws);
        __half* Mh = (__half*)(ws + WS_MH);
        convert_M<<<(D_ * D_ + 255) / 256, 256, 0, stream>>>(M, Mh);
        fused_wave2<<<B_ / 2, 256, 0, stream>>>(inputs, emb, ws, out);
    } else {
        precompute_anchors<<<1, 256, 0, stream>>>(a_emb, seed_w, ws);
        gather_gemm<<<B_ / G_R, 512, 0, stream>>>(inputs, emb, M, ws);
        fused_main<<<B_, 512, 0, stream>>>(inputs, emb, ws, out);
    }
}